// Round 6
// baseline (515.366 us; speedup 1.0000x reference)
//
#include <hip/hip_runtime.h>

#define THREADS 256

// d_out = concat(corr3, corr2, corr1, corr0), fp32.
// corr[bb, pi, pj, i, j] = sum_c a[bb,c,i,j] * bpad[bb,c, i+pi-4, j+pj-4]
// Input mapping (R4 fix): d_in = rgb0, depth0, rgb1, depth1, ... (interleaved).
#define OFF3 0
#define OFF2 127008        // 8*81*14*14
#define OFF1 635040        // OFF2 + 8*81*28*28
#define OFF0 2667168       // OFF1 + 8*81*56*56  (zero-init atomic region end)

__global__ void __launch_bounds__(THREADS)
zero_region_kernel(float* __restrict__ p, int n) {
    int i = blockIdx.x * blockDim.x + threadIdx.x;
    int stride = gridDim.x * blockDim.x;
    for (; i < n; i += stride) p[i] = 0.f;
}

// One block processes (bb, i-tile [i0,i0+TI), channel-chunk ch).
// Thread tid -> (ii in [0,TI), pi in [0,9), strip s in [0,STRIPS)),
// computing acc[9 pj][SJ pixels]. SJ*STRIPS == W.
template<int C, int H, int W, int TI, int SJ, int STRIPS, int CHUNKS, bool ATOMIC>
__global__ void __launch_bounds__(THREADS)
corr_level_kernel(const float* __restrict__ a, const float* __restrict__ b,
                  float* __restrict__ out)
{
    constexpr int PER_I = 9 * STRIPS;
    constexpr int USED  = TI * PER_I;      // <= 256
    constexpr int BW_   = W + 8;           // padded b row width
    constexpr int BROWS = TI + 8;
    constexpr int CCH   = C / CHUNKS;
    constexpr int HT    = H / TI;
    static_assert(USED <= THREADS, "thread mapping overflow");
    static_assert(SJ * STRIPS == W, "strips must cover W");

    __shared__ float b_lds[BROWS * BW_];
    __shared__ float a_lds[TI * W];

    const int blk = blockIdx.x;
    const int ch  = blk % CHUNKS;
    const int t2  = blk / CHUNKS;
    const int it  = t2 % HT;
    const int bb  = t2 / HT;
    const int i0  = it * TI;

    const int tid = threadIdx.x;
    const int ii  = tid / PER_I;
    const int rem = tid - ii * PER_I;
    const int pi  = rem / STRIPS;
    const int s   = rem - pi * STRIPS;
    const int j0  = s * SJ;
    const bool active = (tid < USED);

    const int c0 = ch * CCH;
    const float* __restrict__ bp = b + (size_t)(bb * C + c0) * (H * W);
    const float* __restrict__ ap = a + (size_t)(bb * C + c0) * (H * W);

    float acc[9][SJ];
    #pragma unroll
    for (int p = 0; p < 9; ++p)
        #pragma unroll
        for (int u = 0; u < SJ; ++u) acc[p][u] = 0.f;

    for (int c = 0; c < CCH; ++c) {
        const float* bc = bp + (size_t)c * (H * W);
        const float* ac = ap + (size_t)c * (H * W);
        // ---- stage b rows (zero-padded halo) ----
        for (int base = 0; base < BROWS * BW_; base += THREADS) {
            int idx = base + tid;
            if (base + THREADS <= BROWS * BW_ || idx < BROWS * BW_) {
                int row = idx / BW_;
                int col = idx - row * BW_;
                int r  = i0 + row - 4;
                int jj = col - 4;
                float v = 0.f;
                if ((unsigned)r < (unsigned)H && (unsigned)jj < (unsigned)W)
                    v = bc[r * W + jj];
                b_lds[idx] = v;
            }
        }
        // ---- stage a rows ----
        for (int base = 0; base < TI * W; base += THREADS) {
            int idx = base + tid;
            if (base + THREADS <= TI * W || idx < TI * W) {
                int row = idx / W;
                int col = idx - row * W;
                a_lds[idx] = ac[(i0 + row) * W + col];
            }
        }
        __syncthreads();

        if (active) {
            float breg[SJ + 8];
            float areg[SJ];
            const int bbase = (ii + pi) * BW_ + j0;
            const int abase = ii * W + j0;
            #pragma unroll
            for (int k = 0; k < SJ + 8; ++k) breg[k] = b_lds[bbase + k];
            #pragma unroll
            for (int u = 0; u < SJ; ++u) areg[u] = a_lds[abase + u];
            #pragma unroll
            for (int pj = 0; pj < 9; ++pj)
                #pragma unroll
                for (int u = 0; u < SJ; ++u)
                    acc[pj][u] = fmaf(areg[u], breg[u + pj], acc[pj][u]);
        }
        __syncthreads();
    }

    if (active) {
        const int i = i0 + ii;
        #pragma unroll
        for (int pj = 0; pj < 9; ++pj) {
            float* o = out + ((size_t)((bb * 9 + pi) * 9 + pj) * H + i) * W + j0;
            #pragma unroll
            for (int u = 0; u < SJ; ++u) {
                if constexpr (ATOMIC) atomicAdd(&o[u], acc[pj][u]);
                else                  o[u] = acc[pj][u];
            }
        }
    }
}

extern "C" void kernel_launch(void* const* d_in, const int* in_sizes, int n_in,
                              void* d_out, int out_size, void* d_ws, size_t ws_size,
                              hipStream_t stream) {
    // setup_inputs() dict order: rgb0, depth0, rgb1, depth1, rgb2, depth2, rgb3, depth3
    const float* a0 = (const float*)d_in[0];  // rgb0   [8,64,112,112]
    const float* b0 = (const float*)d_in[1];  // depth0
    const float* a1 = (const float*)d_in[2];  // rgb1   [8,128,56,56]
    const float* b1 = (const float*)d_in[3];  // depth1
    const float* a2 = (const float*)d_in[4];  // rgb2   [8,256,28,28]
    const float* b2 = (const float*)d_in[5];  // depth2
    const float* a3 = (const float*)d_in[6];  // rgb3   [8,512,14,14]
    const float* b3 = (const float*)d_in[7];  // depth3
    float* out = (float*)d_out;

    // zero the atomic-accumulated region (corr3 | corr2 | corr1)
    hipLaunchKernelGGL(zero_region_kernel, dim3(512), dim3(THREADS), 0, stream,
                       out, OFF0);
    // L3: 8 batches * 1 i-tile * 16 chunks = 128 blocks, atomic (32 ch/block)
    hipLaunchKernelGGL((corr_level_kernel<512, 14, 14, 14, 7, 2, 16, true>),
                       dim3(128), dim3(THREADS), 0, stream, a3, b3, out + OFF3);
    // L2: 8 * 7 * 4 = 224 blocks, atomic (64 ch/block)
    hipLaunchKernelGGL((corr_level_kernel<256, 28, 28, 4, 4, 7, 4, true>),
                       dim3(224), dim3(THREADS), 0, stream, a2, b2, out + OFF2);
    // L1: 8 * 14 * 2 = 224 blocks, atomic (64 ch/block)
    hipLaunchKernelGGL((corr_level_kernel<128, 56, 56, 4, 8, 7, 2, true>),
                       dim3(224), dim3(THREADS), 0, stream, a1, b1, out + OFF1);
    // L0: 8 * 56 * 1 = 448 blocks, direct store (64 ch/block)
    hipLaunchKernelGGL((corr_level_kernel<64, 112, 112, 2, 8, 14, 1, false>),
                       dim3(448), dim3(THREADS), 0, stream, a0, b0, out + OFF0);
}

// Round 7
// 334.368 us; speedup vs baseline: 1.5413x; 1.5413x over previous
//
#include <hip/hip_runtime.h>

#define THREADS 256

// d_out = concat(corr3, corr2, corr1, corr0), fp32.
// corr[bb, pi, pj, i, j] = sum_c a[bb,c,i,j] * bpad[bb,c, i+pi-4, j+pj-4]
// Input mapping (R4 fix): d_in = rgb0, depth0, rgb1, depth1, ... (interleaved).
#define OFF3 0
#define OFF2 127008        // 8*81*14*14
#define OFF1 635040        // OFF2 + 8*81*28*28
#define OFF0 2667168       // OFF1 + 8*81*56*56

// Workspace layout (floats): L1 partials | L2 partials | L3 partials
#define N1 2032128
#define N2 508032
#define N3 127008
#define WS_L1 0
#define WS_L2 (2 * N1)              // 4064256
#define WS_L3 (WS_L2 + 4 * N2)      // 6096384
#define WS_FLOATS (WS_L3 + 16 * N3) // 8128512
#define WS_BYTES ((size_t)WS_FLOATS * 4)

__global__ void __launch_bounds__(THREADS)
zero_region_kernel(float* __restrict__ p, int n) {
    int i = blockIdx.x * blockDim.x + threadIdx.x;
    int stride = gridDim.x * blockDim.x;
    for (; i < n; i += stride) p[i] = 0.f;
}

// out[i] = sum_k ws[k*n4 + i]  (float4-vectorized)
__global__ void __launch_bounds__(THREADS)
reduce_partials_kernel(const float4* __restrict__ ws, float4* __restrict__ out,
                       int n4, int chunks) {
    int i = blockIdx.x * blockDim.x + threadIdx.x;
    int stride = gridDim.x * blockDim.x;
    for (; i < n4; i += stride) {
        float4 s = ws[i];
        for (int k = 1; k < chunks; ++k) {
            float4 t = ws[(size_t)k * n4 + i];
            s.x += t.x; s.y += t.y; s.z += t.z; s.w += t.w;
        }
        out[i] = s;
    }
}

// One block processes (bb, i-tile [i0,i0+TI), channel-chunk ch).
// Thread tid -> (ii in [0,TI), pi in [0,9), strip s in [0,STRIPS)),
// computing acc[9 pj][SJ pixels]. SJ*STRIPS == W.
// MODE 0: direct store to out (CHUNKS==1)
// MODE 1: plain store to per-chunk partial region out + ch*NOUT
// MODE 2: atomicAdd into out (fallback when ws too small)
template<int C, int H, int W, int TI, int SJ, int STRIPS, int CHUNKS, int MODE>
__global__ void __launch_bounds__(THREADS)
corr_level_kernel(const float* __restrict__ a, const float* __restrict__ b,
                  float* __restrict__ out)
{
    constexpr int PER_I = 9 * STRIPS;
    constexpr int USED  = TI * PER_I;          // 252 at every level
    constexpr int BW_   = ((W + 8 + 3) / 4) * 4;  // padded b row width (16B-aligned rows)
    constexpr int BROWS = TI + 8;
    constexpr int CCH   = C / CHUNKS;
    constexpr int HT    = H / TI;
    constexpr int NOUT  = 8 * 81 * H * W;
    static_assert(USED <= THREADS, "thread mapping overflow");
    static_assert(SJ * STRIPS == W, "strips must cover W");

    __shared__ float b_lds[BROWS * BW_];
    __shared__ float a_lds[TI * W];

    const int blk = blockIdx.x;
    const int ch  = blk % CHUNKS;
    const int t2  = blk / CHUNKS;
    const int it  = t2 % HT;
    const int bb  = t2 / HT;
    const int i0  = it * TI;

    const int tid = threadIdx.x;
    const int ii  = tid / PER_I;
    const int rem = tid - ii * PER_I;
    const int pi  = rem / STRIPS;
    const int s   = rem - pi * STRIPS;
    const int j0  = s * SJ;
    const bool active = (tid < USED);

    const int c0 = ch * CCH;
    const float* __restrict__ bp = b + (size_t)(bb * C + c0) * (H * W);
    const float* __restrict__ ap = a + (size_t)(bb * C + c0) * (H * W);

    float acc[9][SJ];
    #pragma unroll
    for (int p = 0; p < 9; ++p)
        #pragma unroll
        for (int u = 0; u < SJ; ++u) acc[p][u] = 0.f;

    for (int c = 0; c < CCH; ++c) {
        const float* bc = bp + (size_t)c * (H * W);
        const float* ac = ap + (size_t)c * (H * W);
        // ---- stage b rows (zero-padded halo) ----
        for (int base = 0; base < BROWS * BW_; base += THREADS) {
            int idx = base + tid;
            if (base + THREADS <= BROWS * BW_ || idx < BROWS * BW_) {
                int row = idx / BW_;
                int col = idx - row * BW_;
                int r  = i0 + row - 4;
                int jj = col - 4;
                float v = 0.f;
                if ((unsigned)r < (unsigned)H && (unsigned)jj < (unsigned)W)
                    v = bc[r * W + jj];
                b_lds[idx] = v;
            }
        }
        // ---- stage a rows ----
        for (int base = 0; base < TI * W; base += THREADS) {
            int idx = base + tid;
            if (base + THREADS <= TI * W || idx < TI * W) {
                int row = idx / W;
                int col = idx - row * W;
                a_lds[idx] = ac[(i0 + row) * W + col];
            }
        }
        __syncthreads();

        if (active) {
            float breg[SJ + 8];
            float areg[SJ];
            const int bbase = (ii + pi) * BW_ + j0;
            const int abase = ii * W + j0;
            #pragma unroll
            for (int k = 0; k < SJ + 8; ++k) breg[k] = b_lds[bbase + k];
            #pragma unroll
            for (int u = 0; u < SJ; ++u) areg[u] = a_lds[abase + u];
            #pragma unroll
            for (int pj = 0; pj < 9; ++pj)
                #pragma unroll
                for (int u = 0; u < SJ; ++u)
                    acc[pj][u] = fmaf(areg[u], breg[u + pj], acc[pj][u]);
        }
        __syncthreads();
    }

    if (active) {
        const int i = i0 + ii;
        float* obase = out;
        if constexpr (MODE == 1) obase = out + (size_t)ch * NOUT;
        #pragma unroll
        for (int pj = 0; pj < 9; ++pj) {
            float* o = obase + ((size_t)((bb * 9 + pi) * 9 + pj) * H + i) * W + j0;
            #pragma unroll
            for (int u = 0; u < SJ; ++u) {
                if constexpr (MODE == 2) atomicAdd(&o[u], acc[pj][u]);
                else                     o[u] = acc[pj][u];
            }
        }
    }
}

extern "C" void kernel_launch(void* const* d_in, const int* in_sizes, int n_in,
                              void* d_out, int out_size, void* d_ws, size_t ws_size,
                              hipStream_t stream) {
    // setup_inputs() dict order: rgb0, depth0, rgb1, depth1, rgb2, depth2, rgb3, depth3
    const float* a0 = (const float*)d_in[0];  // rgb0   [8,64,112,112]
    const float* b0 = (const float*)d_in[1];  // depth0
    const float* a1 = (const float*)d_in[2];  // rgb1   [8,128,56,56]
    const float* b1 = (const float*)d_in[3];  // depth1
    const float* a2 = (const float*)d_in[4];  // rgb2   [8,256,28,28]
    const float* b2 = (const float*)d_in[5];  // depth2
    const float* a3 = (const float*)d_in[6];  // rgb3   [8,512,14,14]
    const float* b3 = (const float*)d_in[7];  // depth3
    float* out = (float*)d_out;
    float* ws  = (float*)d_ws;

    if (ws_size >= WS_BYTES) {
        // ---- partial-sum path (no atomics) ----
        // L3: 8*1*16 = 128 blocks -> 16 partials in ws
        hipLaunchKernelGGL((corr_level_kernel<512, 14, 14, 14, 7, 2, 16, 1>),
                           dim3(128), dim3(THREADS), 0, stream, a3, b3, ws + WS_L3);
        // L2: 8*7*4 = 224 blocks -> 4 partials
        hipLaunchKernelGGL((corr_level_kernel<256, 28, 28, 4, 4, 7, 4, 1>),
                           dim3(224), dim3(THREADS), 0, stream, a2, b2, ws + WS_L2);
        // L1: 8*14*2 = 224 blocks -> 2 partials
        hipLaunchKernelGGL((corr_level_kernel<128, 56, 56, 4, 8, 7, 2, 1>),
                           dim3(224), dim3(THREADS), 0, stream, a1, b1, ws + WS_L1);
        // L0: 8*56*1 = 448 blocks, direct store
        hipLaunchKernelGGL((corr_level_kernel<64, 112, 112, 2, 8, 14, 1, 0>),
                           dim3(448), dim3(THREADS), 0, stream, a0, b0, out + OFF0);
        // reductions: ws partials -> d_out regions
        hipLaunchKernelGGL(reduce_partials_kernel, dim3(125), dim3(THREADS), 0, stream,
                           (const float4*)(ws + WS_L3), (float4*)(out + OFF3), N3 / 4, 16);
        hipLaunchKernelGGL(reduce_partials_kernel, dim3(497), dim3(THREADS), 0, stream,
                           (const float4*)(ws + WS_L2), (float4*)(out + OFF2), N2 / 4, 4);
        hipLaunchKernelGGL(reduce_partials_kernel, dim3(1985), dim3(THREADS), 0, stream,
                           (const float4*)(ws + WS_L1), (float4*)(out + OFF1), N1 / 4, 2);
    } else {
        // ---- fallback: atomic path (R6 behavior, correct but slow) ----
        hipLaunchKernelGGL(zero_region_kernel, dim3(512), dim3(THREADS), 0, stream,
                           out, OFF0);
        hipLaunchKernelGGL((corr_level_kernel<512, 14, 14, 14, 7, 2, 16, 2>),
                           dim3(128), dim3(THREADS), 0, stream, a3, b3, out + OFF3);
        hipLaunchKernelGGL((corr_level_kernel<256, 28, 28, 4, 4, 7, 4, 2>),
                           dim3(224), dim3(THREADS), 0, stream, a2, b2, out + OFF2);
        hipLaunchKernelGGL((corr_level_kernel<128, 56, 56, 4, 8, 7, 2, 2>),
                           dim3(224), dim3(THREADS), 0, stream, a1, b1, out + OFF1);
        hipLaunchKernelGGL((corr_level_kernel<64, 112, 112, 2, 8, 14, 1, 0>),
                           dim3(448), dim3(THREADS), 0, stream, a0, b0, out + OFF0);
    }
}

// Round 8
// 177.814 us; speedup vs baseline: 2.8983x; 1.8804x over previous
//
#include <hip/hip_runtime.h>

#define THREADS 256

// d_out = concat(corr3, corr2, corr1, corr0), fp32.
// corr[bb, pi, pj, i, j] = sum_c a[bb,c,i,j] * bpad[bb,c, i+pi-4, j+pj-4]
// Input mapping: d_in = rgb0, depth0, rgb1, depth1, ... (interleaved).
#define OFF3 0
#define OFF2 127008        // 8*81*14*14
#define OFF1 635040        // OFF2 + 8*81*28*28
#define OFF0 2667168       // OFF1 + 8*81*56*56

// Workspace layout (floats): L1 partials | L2 partials | L3 partials
#define N1 2032128
#define N2 508032
#define N3 127008
#define WS_L1 0
#define WS_L2 (2 * N1)
#define WS_L3 (WS_L2 + 4 * N2)
#define WS_FLOATS (WS_L3 + 16 * N3)
#define WS_BYTES ((size_t)WS_FLOATS * 4)

__global__ void __launch_bounds__(THREADS)
zero_region_kernel(float* __restrict__ p, int n) {
    int i = blockIdx.x * blockDim.x + threadIdx.x;
    int stride = gridDim.x * blockDim.x;
    for (; i < n; i += stride) p[i] = 0.f;
}

// out[i] = sum_k ws[k*n4 + i]  (float4-vectorized)
__global__ void __launch_bounds__(THREADS)
reduce_partials_kernel(const float4* __restrict__ ws, float4* __restrict__ out,
                       int n4, int chunks) {
    int i = blockIdx.x * blockDim.x + threadIdx.x;
    int stride = gridDim.x * blockDim.x;
    for (; i < n4; i += stride) {
        float4 s = ws[i];
        for (int k = 1; k < chunks; ++k) {
            float4 t = ws[(size_t)k * n4 + i];
            s.x += t.x; s.y += t.y; s.z += t.z; s.w += t.w;
        }
        out[i] = s;
    }
}

// Block = (bb, i-tile, channel-chunk). Thread tid -> (ii, pi, strip s).
// CB channels staged per barrier pair (amortizes barrier-latency).
// MODE 0: direct store; MODE 1: per-chunk partial region; MODE 2: atomicAdd.
template<int C, int H, int W, int TI, int SJ, int STRIPS, int CHUNKS, int CB, int MODE>
__global__ void __launch_bounds__(THREADS)
corr_level_kernel(const float* __restrict__ a, const float* __restrict__ b,
                  float* __restrict__ out)
{
    constexpr int PER_I = 9 * STRIPS;
    constexpr int USED  = TI * PER_I;              // 252 at every level
    constexpr int BW_   = ((W + 8 + 3) / 4) * 4;   // padded b row width
    constexpr int BROWS = TI + 8;
    constexpr int CCH   = C / CHUNKS;
    constexpr int HT    = H / TI;
    constexpr int NOUT  = 8 * 81 * H * W;
    constexpr int HW    = H * W;
    constexpr int BPC   = BROWS * BW_;             // b floats per channel
    constexpr int APC   = TI * W;                  // a floats per channel
    constexpr bool F4   = (W % 4 == 0);            // vectorized staging path
    static_assert(USED <= THREADS, "thread mapping overflow");
    static_assert(SJ * STRIPS == W, "strips must cover W");
    static_assert(CCH % CB == 0, "CB must divide channels per chunk");

    __shared__ float b_lds[CB * BPC];
    __shared__ float a_lds[CB * APC];

    const int blk = blockIdx.x;
    const int ch  = blk % CHUNKS;
    const int t2  = blk / CHUNKS;
    const int it  = t2 % HT;
    const int bb  = t2 / HT;
    const int i0  = it * TI;

    const int tid = threadIdx.x;
    const int ii  = tid / PER_I;
    const int rem = tid - ii * PER_I;
    const int pi  = rem / STRIPS;
    const int s   = rem - pi * STRIPS;
    const int j0  = s * SJ;
    const bool active = (tid < USED);

    const int c0 = ch * CCH;
    const float* __restrict__ bp = b + (size_t)(bb * C + c0) * HW;
    const float* __restrict__ ap = a + (size_t)(bb * C + c0) * HW;

    float acc[9][SJ];
    #pragma unroll
    for (int p = 0; p < 9; ++p)
        #pragma unroll
        for (int u = 0; u < SJ; ++u) acc[p][u] = 0.f;

    for (int cg = 0; cg < CCH / CB; ++cg) {
        const float* bg = bp + (size_t)(cg * CB) * HW;
        const float* ag = ap + (size_t)(cg * CB) * HW;

        if constexpr (F4) {
            // ---- b staging, float4: first/last f4 of each row = halo zeros,
            //      interior f4 k reads aligned global at jj=(k-1)*4 ----
            constexpr int F4PR = BW_ / 4;
            constexpr int NBF4 = BROWS * F4PR;
            for (int f = tid; f < CB * NBF4; f += THREADS) {
                const int cb = f / NBF4;
                const int f2 = f - cb * NBF4;
                const int row = f2 / F4PR;
                const int c4  = f2 - row * F4PR;
                const int r   = i0 + row - 4;
                const int jj  = (c4 - 1) * 4;
                float4 v = {0.f, 0.f, 0.f, 0.f};
                if ((unsigned)r < (unsigned)H && c4 >= 1 && jj < W)
                    v = *reinterpret_cast<const float4*>(&bg[(size_t)cb * HW + r * W + jj]);
                *reinterpret_cast<float4*>(&b_lds[cb * BPC + row * BW_ + c4 * 4]) = v;
            }
            // ---- a staging, float4 (always aligned, always in-bounds) ----
            constexpr int W4   = W / 4;
            constexpr int NAF4 = TI * W4;
            for (int f = tid; f < CB * NAF4; f += THREADS) {
                const int cb = f / NAF4;
                const int f2 = f - cb * NAF4;
                const int row = f2 / W4;
                const int c4  = f2 - row * W4;
                float4 v = *reinterpret_cast<const float4*>(
                    &ag[(size_t)cb * HW + (i0 + row) * W + c4 * 4]);
                *reinterpret_cast<float4*>(&a_lds[cb * APC + row * W + c4 * 4]) = v;
            }
        } else {
            // ---- scalar staging (W not divisible by 4: L3) ----
            for (int f = tid; f < CB * BPC; f += THREADS) {
                const int cb = f / BPC;
                const int f2 = f - cb * BPC;
                const int row = f2 / BW_;
                const int col = f2 - row * BW_;
                const int r  = i0 + row - 4;
                const int jj = col - 4;
                float v = 0.f;
                if ((unsigned)r < (unsigned)H && (unsigned)jj < (unsigned)W)
                    v = bg[(size_t)cb * HW + r * W + jj];
                b_lds[cb * BPC + row * BW_ + col] = v;
            }
            for (int f = tid; f < CB * APC; f += THREADS) {
                const int cb = f / APC;
                const int f2 = f - cb * APC;
                const int row = f2 / W;
                const int col = f2 - row * W;
                a_lds[cb * APC + row * W + col] = ag[(size_t)cb * HW + (i0 + row) * W + col];
            }
        }
        __syncthreads();

        if (active) {
            #pragma unroll
            for (int cb = 0; cb < CB; ++cb) {
                float breg[SJ + 8];
                float areg[SJ];
                const float* bbase = &b_lds[cb * BPC + (ii + pi) * BW_ + j0];
                const float* abase = &a_lds[cb * APC + ii * W + j0];
                if constexpr (F4 && ((SJ + 8) % 4 == 0) && (SJ % 4 == 0)) {
                    #pragma unroll
                    for (int k = 0; k < (SJ + 8) / 4; ++k) {
                        float4 t = *reinterpret_cast<const float4*>(&bbase[4 * k]);
                        breg[4*k+0] = t.x; breg[4*k+1] = t.y;
                        breg[4*k+2] = t.z; breg[4*k+3] = t.w;
                    }
                    #pragma unroll
                    for (int u = 0; u < SJ / 4; ++u) {
                        float4 t = *reinterpret_cast<const float4*>(&abase[4 * u]);
                        areg[4*u+0] = t.x; areg[4*u+1] = t.y;
                        areg[4*u+2] = t.z; areg[4*u+3] = t.w;
                    }
                } else {
                    #pragma unroll
                    for (int k = 0; k < SJ + 8; ++k) breg[k] = bbase[k];
                    #pragma unroll
                    for (int u = 0; u < SJ; ++u) areg[u] = abase[u];
                }
                #pragma unroll
                for (int pj = 0; pj < 9; ++pj)
                    #pragma unroll
                    for (int u = 0; u < SJ; ++u)
                        acc[pj][u] = fmaf(areg[u], breg[u + pj], acc[pj][u]);
            }
        }
        __syncthreads();
    }

    if (active) {
        const int i = i0 + ii;
        float* obase = out;
        if constexpr (MODE == 1) obase = out + (size_t)ch * NOUT;
        #pragma unroll
        for (int pj = 0; pj < 9; ++pj) {
            float* o = obase + ((size_t)((bb * 9 + pi) * 9 + pj) * H + i) * W + j0;
            if constexpr (MODE == 2) {
                #pragma unroll
                for (int u = 0; u < SJ; ++u) atomicAdd(&o[u], acc[pj][u]);
            } else if constexpr (F4 && (SJ % 4 == 0)) {
                #pragma unroll
                for (int u = 0; u < SJ / 4; ++u) {
                    float4 t;
                    t.x = acc[pj][4*u+0]; t.y = acc[pj][4*u+1];
                    t.z = acc[pj][4*u+2]; t.w = acc[pj][4*u+3];
                    *reinterpret_cast<float4*>(&o[4 * u]) = t;
                }
            } else {
                #pragma unroll
                for (int u = 0; u < SJ; ++u) o[u] = acc[pj][u];
            }
        }
    }
}

extern "C" void kernel_launch(void* const* d_in, const int* in_sizes, int n_in,
                              void* d_out, int out_size, void* d_ws, size_t ws_size,
                              hipStream_t stream) {
    // setup_inputs() dict order: rgb0, depth0, rgb1, depth1, rgb2, depth2, rgb3, depth3
    const float* a0 = (const float*)d_in[0];
    const float* b0 = (const float*)d_in[1];
    const float* a1 = (const float*)d_in[2];
    const float* b1 = (const float*)d_in[3];
    const float* a2 = (const float*)d_in[4];
    const float* b2 = (const float*)d_in[5];
    const float* a3 = (const float*)d_in[6];
    const float* b3 = (const float*)d_in[7];
    float* out = (float*)d_out;
    float* ws  = (float*)d_ws;

    if (ws_size >= WS_BYTES) {
        // ---- partial-sum path (no atomics) ----
        hipLaunchKernelGGL((corr_level_kernel<512, 14, 14, 14, 7, 2, 16, 8, 1>),
                           dim3(128), dim3(THREADS), 0, stream, a3, b3, ws + WS_L3);
        hipLaunchKernelGGL((corr_level_kernel<256, 28, 28, 4, 4, 7, 4, 8, 1>),
                           dim3(224), dim3(THREADS), 0, stream, a2, b2, ws + WS_L2);
        hipLaunchKernelGGL((corr_level_kernel<128, 56, 56, 4, 8, 7, 2, 8, 1>),
                           dim3(224), dim3(THREADS), 0, stream, a1, b1, ws + WS_L1);
        hipLaunchKernelGGL((corr_level_kernel<64, 112, 112, 2, 8, 14, 1, 8, 0>),
                           dim3(448), dim3(THREADS), 0, stream, a0, b0, out + OFF0);
        hipLaunchKernelGGL(reduce_partials_kernel, dim3(125), dim3(THREADS), 0, stream,
                           (const float4*)(ws + WS_L3), (float4*)(out + OFF3), N3 / 4, 16);
        hipLaunchKernelGGL(reduce_partials_kernel, dim3(497), dim3(THREADS), 0, stream,
                           (const float4*)(ws + WS_L2), (float4*)(out + OFF2), N2 / 4, 4);
        hipLaunchKernelGGL(reduce_partials_kernel, dim3(1985), dim3(THREADS), 0, stream,
                           (const float4*)(ws + WS_L1), (float4*)(out + OFF1), N1 / 4, 2);
    } else {
        // ---- fallback: atomic path ----
        hipLaunchKernelGGL(zero_region_kernel, dim3(512), dim3(THREADS), 0, stream,
                           out, OFF0);
        hipLaunchKernelGGL((corr_level_kernel<512, 14, 14, 14, 7, 2, 16, 8, 2>),
                           dim3(128), dim3(THREADS), 0, stream, a3, b3, out + OFF3);
        hipLaunchKernelGGL((corr_level_kernel<256, 28, 28, 4, 4, 7, 4, 8, 2>),
                           dim3(224), dim3(THREADS), 0, stream, a2, b2, out + OFF2);
        hipLaunchKernelGGL((corr_level_kernel<128, 56, 56, 4, 8, 7, 2, 8, 2>),
                           dim3(224), dim3(THREADS), 0, stream, a1, b1, out + OFF1);
        hipLaunchKernelGGL((corr_level_kernel<64, 112, 112, 2, 8, 14, 1, 8, 0>),
                           dim3(448), dim3(THREADS), 0, stream, a0, b0, out + OFF0);
    }
}

// Round 9
// 124.897 us; speedup vs baseline: 4.1263x; 1.4237x over previous
//
#include <hip/hip_runtime.h>

#define THREADS 256

// d_out = concat(corr3, corr2, corr1, corr0), fp32.
// corr[bb, pi, pj, i, j] = sum_c a[bb,c,i,j] * bpad[bb,c, i+pi-4, j+pj-4]
// Input mapping: d_in = rgb0, depth0, rgb1, depth1, ... (interleaved).
#define OFF3 0
#define OFF2 127008        // 8*81*14*14
#define OFF1 635040        // OFF2 + 8*81*28*28
#define OFF0 2667168       // OFF1 + 8*81*56*56

// Workspace layout (floats): L1 partials | L2 partials | L3 partials
#define N1 2032128
#define N2 508032
#define N3 127008
#define WS_L1 0
#define WS_L2 (2 * N1)
#define WS_L3 (WS_L2 + 4 * N2)
#define WS_FLOATS (WS_L3 + 16 * N3)
#define WS_BYTES ((size_t)WS_FLOATS * 4)

__global__ void __launch_bounds__(THREADS)
zero_region_kernel(float* __restrict__ p, int n) {
    int i = blockIdx.x * blockDim.x + threadIdx.x;
    int stride = gridDim.x * blockDim.x;
    for (; i < n; i += stride) p[i] = 0.f;
}

// out[i] = sum_k ws[k*n4 + i]  (float4-vectorized)
__global__ void __launch_bounds__(THREADS)
reduce_partials_kernel(const float4* __restrict__ ws, float4* __restrict__ out,
                       int n4, int chunks) {
    int i = blockIdx.x * blockDim.x + threadIdx.x;
    int stride = gridDim.x * blockDim.x;
    for (; i < n4; i += stride) {
        float4 s = ws[i];
        for (int k = 1; k < chunks; ++k) {
            float4 t = ws[(size_t)k * n4 + i];
            s.x += t.x; s.y += t.y; s.z += t.z; s.w += t.w;
        }
        out[i] = s;
    }
}

// Block = (bb, i-tile, channel-chunk). Thread tid -> (ii, pi, strip s).
// b staged in LDS with T14 register-prefetch (load group cg+1 during compute of cg).
// a read directly from global during compute (L1 serves the 9-way pi reuse).
// MODE 0: direct store; MODE 1: per-chunk partial region; MODE 2: atomicAdd.
template<int C, int H, int W, int TI, int SJ, int STRIPS, int CHUNKS, int CB, int MODE>
__global__ void __launch_bounds__(THREADS)
corr_level_kernel(const float* __restrict__ a, const float* __restrict__ b,
                  float* __restrict__ out)
{
    constexpr int PER_I = 9 * STRIPS;
    constexpr int USED  = TI * PER_I;              // 252 at every level
    constexpr int BW_   = ((W + 8 + 3) / 4) * 4;   // padded b row width
    constexpr int BROWS = TI + 8;
    constexpr int CCH   = C / CHUNKS;
    constexpr int HT    = H / TI;
    constexpr int NOUT  = 8 * 81 * H * W;
    constexpr int HW    = H * W;
    constexpr int BPC   = BROWS * BW_;             // b floats per channel
    constexpr bool F4   = (W % 4 == 0);            // vectorized path (L0/L1/L2)
    constexpr int NG    = CCH / CB;                // channel groups per block
    static_assert(USED <= THREADS, "thread mapping overflow");
    static_assert(SJ * STRIPS == W, "strips must cover W");
    static_assert(CCH % CB == 0, "CB must divide channels per chunk");

    __shared__ float b_lds[CB * BPC];

    const int blk = blockIdx.x;
    const int ch  = blk % CHUNKS;
    const int t2  = blk / CHUNKS;
    const int it  = t2 % HT;
    const int bb  = t2 / HT;
    const int i0  = it * TI;

    const int tid = threadIdx.x;
    const int ii  = tid / PER_I;
    const int rem = tid - ii * PER_I;
    const int pi  = rem / STRIPS;
    const int s   = rem - pi * STRIPS;
    const int j0  = s * SJ;
    const bool active = (tid < USED);

    const int c0 = ch * CCH;
    const float* __restrict__ bp = b + (size_t)(bb * C + c0) * HW;
    const float* __restrict__ ap = a + (size_t)(bb * C + c0) * HW;

    float acc[9][SJ];
    #pragma unroll
    for (int p = 0; p < 9; ++p)
        #pragma unroll
        for (int u = 0; u < SJ; ++u) acc[p][u] = 0.f;

    // ---------- staging machinery (b only) ----------
    constexpr int F4PR = BW_ / 4;                  // f4 per b row
    constexpr int NBF4 = BROWS * F4PR;             // f4 per channel
    constexpr int TOT4 = CB * NBF4;                // f4 per group
    constexpr int K4   = (TOT4 + THREADS - 1) / THREADS;
    constexpr int TOTS = CB * BPC;                 // scalar floats per group
    constexpr int KS   = (TOTS + THREADS - 1) / THREADS;

    float4 pre4[F4 ? K4 : 1];
    float  pres[F4 ? 1 : KS];

    auto load_group = [&](int cg) {
        if constexpr (F4) {
            const float* bg = bp + (size_t)(cg * CB) * HW;
            #pragma unroll
            for (int k = 0; k < K4; ++k) {
                const int f = tid + k * THREADS;
                float4 v = {0.f, 0.f, 0.f, 0.f};
                if (f < TOT4) {
                    const int cb  = f / NBF4;
                    const int f2  = f - cb * NBF4;
                    const int row = f2 / F4PR;
                    const int c4  = f2 - row * F4PR;
                    const int r   = i0 + row - 4;
                    const int jj  = (c4 - 1) * 4;
                    if ((unsigned)r < (unsigned)H && c4 >= 1 && jj < W)
                        v = *reinterpret_cast<const float4*>(&bg[(size_t)cb * HW + r * W + jj]);
                }
                pre4[k] = v;
            }
        } else {
            const float* bg = bp + (size_t)(cg * CB) * HW;
            #pragma unroll
            for (int k = 0; k < KS; ++k) {
                const int f = tid + k * THREADS;
                float v = 0.f;
                if (f < TOTS) {
                    const int cb  = f / BPC;
                    const int f2  = f - cb * BPC;
                    const int row = f2 / BW_;
                    const int col = f2 - row * BW_;
                    const int r   = i0 + row - 4;
                    const int jj  = col - 4;
                    if ((unsigned)r < (unsigned)H && (unsigned)jj < (unsigned)W)
                        v = bg[(size_t)cb * HW + r * W + jj];
                }
                pres[k] = v;
            }
        }
    };
    auto store_group = [&]() {
        if constexpr (F4) {
            #pragma unroll
            for (int k = 0; k < K4; ++k) {
                const int f = tid + k * THREADS;
                if (f < TOT4) {
                    const int cb  = f / NBF4;
                    const int f2  = f - cb * NBF4;
                    const int row = f2 / F4PR;
                    const int c4  = f2 - row * F4PR;
                    *reinterpret_cast<float4*>(&b_lds[cb * BPC + row * BW_ + c4 * 4]) = pre4[k];
                }
            }
        } else {
            #pragma unroll
            for (int k = 0; k < KS; ++k) {
                const int f = tid + k * THREADS;
                if (f < TOTS) pres[k], b_lds[f] = pres[k];
            }
        }
    };

    load_group(0);
    for (int cg = 0; cg < NG; ++cg) {
        store_group();
        __syncthreads();
        if (cg + 1 < NG) load_group(cg + 1);   // T14: prefetch under compute

        if (active) {
            const float* agbase = ap + (size_t)(cg * CB) * HW + (size_t)(i0 + ii) * W + j0;
            #pragma unroll
            for (int cb = 0; cb < CB; ++cb) {
                float breg[SJ + 8];
                float areg[SJ];
                const float* bbase = &b_lds[cb * BPC + (ii + pi) * BW_ + j0];
                const float* ac    = agbase + (size_t)cb * HW;
                if constexpr (F4 && ((SJ + 8) % 4 == 0) && (SJ % 4 == 0)) {
                    #pragma unroll
                    for (int k = 0; k < (SJ + 8) / 4; ++k) {
                        float4 t = *reinterpret_cast<const float4*>(&bbase[4 * k]);
                        breg[4*k+0] = t.x; breg[4*k+1] = t.y;
                        breg[4*k+2] = t.z; breg[4*k+3] = t.w;
                    }
                    #pragma unroll
                    for (int u = 0; u < SJ / 4; ++u) {
                        float4 t = *reinterpret_cast<const float4*>(&ac[4 * u]);
                        areg[4*u+0] = t.x; areg[4*u+1] = t.y;
                        areg[4*u+2] = t.z; areg[4*u+3] = t.w;
                    }
                } else {
                    #pragma unroll
                    for (int k = 0; k < SJ + 8; ++k) breg[k] = bbase[k];
                    #pragma unroll
                    for (int u = 0; u < SJ; ++u) areg[u] = ac[u];
                }
                #pragma unroll
                for (int pj = 0; pj < 9; ++pj)
                    #pragma unroll
                    for (int u = 0; u < SJ; ++u)
                        acc[pj][u] = fmaf(areg[u], breg[u + pj], acc[pj][u]);
            }
        }
        __syncthreads();
    }

    if (active) {
        const int i = i0 + ii;
        float* obase = out;
        if constexpr (MODE == 1) obase = out + (size_t)ch * NOUT;
        #pragma unroll
        for (int pj = 0; pj < 9; ++pj) {
            float* o = obase + ((size_t)((bb * 9 + pi) * 9 + pj) * H + i) * W + j0;
            if constexpr (MODE == 2) {
                #pragma unroll
                for (int u = 0; u < SJ; ++u) atomicAdd(&o[u], acc[pj][u]);
            } else if constexpr (F4 && (SJ % 4 == 0)) {
                #pragma unroll
                for (int u = 0; u < SJ / 4; ++u) {
                    float4 t;
                    t.x = acc[pj][4*u+0]; t.y = acc[pj][4*u+1];
                    t.z = acc[pj][4*u+2]; t.w = acc[pj][4*u+3];
                    *reinterpret_cast<float4*>(&o[4 * u]) = t;
                }
            } else {
                #pragma unroll
                for (int u = 0; u < SJ; ++u) o[u] = acc[pj][u];
            }
        }
    }
}

extern "C" void kernel_launch(void* const* d_in, const int* in_sizes, int n_in,
                              void* d_out, int out_size, void* d_ws, size_t ws_size,
                              hipStream_t stream) {
    // setup_inputs() dict order: rgb0, depth0, rgb1, depth1, rgb2, depth2, rgb3, depth3
    const float* a0 = (const float*)d_in[0];
    const float* b0 = (const float*)d_in[1];
    const float* a1 = (const float*)d_in[2];
    const float* b1 = (const float*)d_in[3];
    const float* a2 = (const float*)d_in[4];
    const float* b2 = (const float*)d_in[5];
    const float* a3 = (const float*)d_in[6];
    const float* b3 = (const float*)d_in[7];
    float* out = (float*)d_out;
    float* ws  = (float*)d_ws;

    if (ws_size >= WS_BYTES) {
        // ---- partial-sum path (no atomics) ----
        hipLaunchKernelGGL((corr_level_kernel<512, 14, 14, 14, 7, 2, 16, 8, 1>),
                           dim3(128), dim3(THREADS), 0, stream, a3, b3, ws + WS_L3);
        hipLaunchKernelGGL((corr_level_kernel<256, 28, 28, 4, 4, 7, 4, 8, 1>),
                           dim3(224), dim3(THREADS), 0, stream, a2, b2, ws + WS_L2);
        hipLaunchKernelGGL((corr_level_kernel<128, 56, 56, 4, 8, 7, 2, 8, 1>),
                           dim3(224), dim3(THREADS), 0, stream, a1, b1, ws + WS_L1);
        hipLaunchKernelGGL((corr_level_kernel<64, 112, 112, 2, 8, 14, 1, 8, 0>),
                           dim3(448), dim3(THREADS), 0, stream, a0, b0, out + OFF0);
        hipLaunchKernelGGL(reduce_partials_kernel, dim3(125), dim3(THREADS), 0, stream,
                           (const float4*)(ws + WS_L3), (float4*)(out + OFF3), N3 / 4, 16);
        hipLaunchKernelGGL(reduce_partials_kernel, dim3(497), dim3(THREADS), 0, stream,
                           (const float4*)(ws + WS_L2), (float4*)(out + OFF2), N2 / 4, 4);
        hipLaunchKernelGGL(reduce_partials_kernel, dim3(1985), dim3(THREADS), 0, stream,
                           (const float4*)(ws + WS_L1), (float4*)(out + OFF1), N1 / 4, 2);
    } else {
        // ---- fallback: atomic path ----
        hipLaunchKernelGGL(zero_region_kernel, dim3(512), dim3(THREADS), 0, stream,
                           out, OFF0);
        hipLaunchKernelGGL((corr_level_kernel<512, 14, 14, 14, 7, 2, 16, 8, 2>),
                           dim3(128), dim3(THREADS), 0, stream, a3, b3, out + OFF3);
        hipLaunchKernelGGL((corr_level_kernel<256, 28, 28, 4, 4, 7, 4, 8, 2>),
                           dim3(224), dim3(THREADS), 0, stream, a2, b2, out + OFF2);
        hipLaunchKernelGGL((corr_level_kernel<128, 56, 56, 4, 8, 7, 2, 8, 2>),
                           dim3(224), dim3(THREADS), 0, stream, a1, b1, out + OFF1);
        hipLaunchKernelGGL((corr_level_kernel<64, 112, 112, 2, 8, 14, 1, 8, 0>),
                           dim3(448), dim3(THREADS), 0, stream, a0, b0, out + OFF0);
    }
}

// Round 10
// 116.751 us; speedup vs baseline: 4.4142x; 1.0698x over previous
//
#include <hip/hip_runtime.h>

#define THREADS 256

// d_out = concat(corr3, corr2, corr1, corr0), fp32.
// corr[bb, pi, pj, i, j] = sum_c a[bb,c,i,j] * bpad[bb,c, i+pi-4, j+pj-4]
// Input mapping: d_in = rgb0, depth0, rgb1, depth1, ... (interleaved).
#define OFF3 0
#define OFF2 127008        // 8*81*14*14
#define OFF1 635040        // OFF2 + 8*81*28*28
#define OFF0 2667168       // OFF1 + 8*81*56*56

// Workspace layout (floats): L1 partials | L2 partials | L3 partials
#define N1 2032128
#define N2 508032
#define N3 127008
#define WS_L1 0
#define WS_L2 (2 * N1)
#define WS_L3 (WS_L2 + 4 * N2)
#define WS_FLOATS (WS_L3 + 16 * N3)
#define WS_BYTES ((size_t)WS_FLOATS * 4)

// fused-grid segmentation
#define GB_L0 896          // 8 bb * 56 i-tiles * 2 j-tiles
#define GB_L1 448          // 8 * 14 * 2 * 2 chunks
#define GB_L2 224          // 8 * 7 * 4 chunks
#define GB_L3 128          // 8 * 16 chunks
#define GB_TOT (GB_L0 + GB_L1 + GB_L2 + GB_L3)   // 1696

#define SMEM_FLOATS 5120   // max over levels: L0 = 8ch * (10 rows * 64)

__global__ void __launch_bounds__(THREADS)
zero_region_kernel(float* __restrict__ p, int n) {
    int i = blockIdx.x * blockDim.x + threadIdx.x;
    int stride = gridDim.x * blockDim.x;
    for (; i < n; i += stride) p[i] = 0.f;
}

// Block = (bb, i-tile, j-tile, channel-chunk). Thread tid -> (ii, pi, strip s).
// F4 levels: b staged in LDS via register prefetch (load cg+1 during compute cg);
// a read directly from global in the compute phase (L1/L2 serve the pi-reuse).
// MODE 0: direct store; MODE 1: per-chunk partial region; MODE 2: atomicAdd.
template<int C, int H, int W, int TI, int TW, int SJ, int STRIPS, int CHUNKS,
         int CB, int MODE>
__device__ __forceinline__ void corr_level(const float* __restrict__ a,
                                           const float* __restrict__ b,
                                           float* __restrict__ out,
                                           int blk, float* __restrict__ smem)
{
    constexpr int PER_I = 9 * STRIPS;
    constexpr int USED  = TI * PER_I;              // 252 at every level
    constexpr int BW_   = ((TW + 8 + 3) / 4) * 4;  // padded staged row width
    constexpr int BROWS = TI + 8;
    constexpr int CCH   = C / CHUNKS;
    constexpr int HT    = H / TI;
    constexpr int WT    = W / TW;
    constexpr int NOUT  = 8 * 81 * H * W;
    constexpr int HW    = H * W;
    constexpr int BPC   = BROWS * BW_;             // staged floats per channel
    constexpr bool F4   = (W % 4 == 0) && (TW % 4 == 0) && (SJ % 4 == 0);
    constexpr int NG    = CCH / CB;
    static_assert(USED <= THREADS, "thread mapping overflow");
    static_assert(SJ * STRIPS == TW, "strips must cover TW");
    static_assert(CCH % CB == 0, "CB must divide channels per chunk");
    static_assert(CB * BPC <= SMEM_FLOATS, "smem overflow");

    const int ch = blk % CHUNKS;
    int t = blk / CHUNKS;
    const int jt = t % WT; t /= WT;
    const int it = t % HT;
    const int bb = t / HT;
    const int i0 = it * TI;
    const int jb = jt * TW;

    const int tid = threadIdx.x;
    const int ii  = tid / PER_I;
    const int rem = tid - ii * PER_I;
    const int pi  = rem / STRIPS;
    const int s   = rem - pi * STRIPS;
    const int j0  = s * SJ;
    const bool active = (tid < USED);

    const int c0 = ch * CCH;
    const float* __restrict__ bp = b + (size_t)(bb * C + c0) * HW;
    const float* __restrict__ ap = a + (size_t)(bb * C + c0) * HW;

    float acc[9][SJ];
    #pragma unroll
    for (int p = 0; p < 9; ++p)
        #pragma unroll
        for (int u = 0; u < SJ; ++u) acc[p][u] = 0.f;

    if constexpr (F4) {
        constexpr int F4PR = BW_ / 4;              // float4 per staged row
        constexpr int NBF4 = BROWS * F4PR;         // float4 per channel
        constexpr int TOT4 = CB * NBF4;            // float4 per group
        constexpr int K4   = (TOT4 + THREADS - 1) / THREADS;

        float4 pre4[K4];
        auto load_group = [&](int cg) {
            const float* bg = bp + (size_t)(cg * CB) * HW;
            #pragma unroll
            for (int k = 0; k < K4; ++k) {
                const int f = tid + k * THREADS;
                float4 v = {0.f, 0.f, 0.f, 0.f};
                if (f < TOT4) {
                    const int cb  = f / NBF4;
                    const int f2  = f - cb * NBF4;
                    const int row = f2 / F4PR;
                    const int c4  = f2 - row * F4PR;
                    const int r   = i0 + row - 4;
                    const int jj  = jb + (c4 - 1) * 4;
                    if ((unsigned)r < (unsigned)H && jj >= 0 && jj < W)
                        v = *reinterpret_cast<const float4*>(&bg[(size_t)cb * HW + r * W + jj]);
                }
                pre4[k] = v;
            }
        };
        auto store_group = [&]() {
            #pragma unroll
            for (int k = 0; k < K4; ++k) {
                const int f = tid + k * THREADS;
                if (f < TOT4) {
                    const int cb  = f / NBF4;
                    const int f2  = f - cb * NBF4;
                    const int row = f2 / F4PR;
                    const int c4  = f2 - row * F4PR;
                    *reinterpret_cast<float4*>(&smem[cb * BPC + row * BW_ + c4 * 4]) = pre4[k];
                }
            }
        };

        load_group(0);
        for (int cg = 0; cg < NG; ++cg) {
            store_group();
            __syncthreads();
            if (cg + 1 < NG) load_group(cg + 1);   // prefetch under compute

            if (active) {
                const float* agbase = ap + (size_t)(cg * CB) * HW
                                    + (size_t)(i0 + ii) * W + jb + j0;
                #pragma unroll
                for (int cb = 0; cb < CB; ++cb) {
                    float breg[SJ + 8];
                    float areg[SJ];
                    const float* bbase = &smem[cb * BPC + (ii + pi) * BW_ + j0];
                    const float* ac    = agbase + (size_t)cb * HW;
                    #pragma unroll
                    for (int k = 0; k < (SJ + 8) / 4; ++k) {
                        float4 v = *reinterpret_cast<const float4*>(&bbase[4 * k]);
                        breg[4*k+0] = v.x; breg[4*k+1] = v.y;
                        breg[4*k+2] = v.z; breg[4*k+3] = v.w;
                    }
                    #pragma unroll
                    for (int u = 0; u < SJ / 4; ++u) {
                        float4 v = *reinterpret_cast<const float4*>(&ac[4 * u]);
                        areg[4*u+0] = v.x; areg[4*u+1] = v.y;
                        areg[4*u+2] = v.z; areg[4*u+3] = v.w;
                    }
                    #pragma unroll
                    for (int pj = 0; pj < 9; ++pj)
                        #pragma unroll
                        for (int u = 0; u < SJ; ++u)
                            acc[pj][u] = fmaf(areg[u], breg[u + pj], acc[pj][u]);
                }
            }
            __syncthreads();
        }
    } else {
        // scalar path (L3: W=14) — direct stage, no register prefetch
        for (int cg = 0; cg < NG; ++cg) {
            const float* bg = bp + (size_t)(cg * CB) * HW;
            for (int f = tid; f < CB * BPC; f += THREADS) {
                const int cb  = f / BPC;
                const int f2  = f - cb * BPC;
                const int row = f2 / BW_;
                const int col = f2 - row * BW_;
                const int r   = i0 + row - 4;
                const int jj  = jb + col - 4;
                float v = 0.f;
                if ((unsigned)r < (unsigned)H && (unsigned)jj < (unsigned)W)
                    v = bg[(size_t)cb * HW + r * W + jj];
                smem[f] = v;
            }
            __syncthreads();
            if (active) {
                const float* agbase = ap + (size_t)(cg * CB) * HW
                                    + (size_t)(i0 + ii) * W + jb + j0;
                #pragma unroll
                for (int cb = 0; cb < CB; ++cb) {
                    float breg[SJ + 8];
                    float areg[SJ];
                    const float* bbase = &smem[cb * BPC + (ii + pi) * BW_ + j0];
                    const float* ac    = agbase + (size_t)cb * HW;
                    #pragma unroll
                    for (int k = 0; k < SJ + 8; ++k) breg[k] = bbase[k];
                    #pragma unroll
                    for (int u = 0; u < SJ; ++u) areg[u] = ac[u];
                    #pragma unroll
                    for (int pj = 0; pj < 9; ++pj)
                        #pragma unroll
                        for (int u = 0; u < SJ; ++u)
                            acc[pj][u] = fmaf(areg[u], breg[u + pj], acc[pj][u]);
                }
            }
            __syncthreads();
        }
    }

    if (active) {
        const int i = i0 + ii;
        float* obase = out;
        if constexpr (MODE == 1) obase = out + (size_t)ch * NOUT;
        #pragma unroll
        for (int pj = 0; pj < 9; ++pj) {
            float* o = obase + ((size_t)((bb * 9 + pi) * 9 + pj) * H + i) * W + jb + j0;
            if constexpr (MODE == 2) {
                #pragma unroll
                for (int u = 0; u < SJ; ++u) atomicAdd(&o[u], acc[pj][u]);
            } else if constexpr (F4) {
                #pragma unroll
                for (int u = 0; u < SJ / 4; ++u) {
                    float4 v;
                    v.x = acc[pj][4*u+0]; v.y = acc[pj][4*u+1];
                    v.z = acc[pj][4*u+2]; v.w = acc[pj][4*u+3];
                    *reinterpret_cast<float4*>(&o[4 * u]) = v;
                }
            } else {
                #pragma unroll
                for (int u = 0; u < SJ; ++u) o[u] = acc[pj][u];
            }
        }
    }
}

// All four levels in ONE dispatch so the small grids overlap with L0.
// PMODE: 1 = ws partial-sum path, 2 = atomic fallback (L0 is MODE 0 in both).
template<int PMODE>
__global__ void __launch_bounds__(THREADS)
corr_fused(const float* __restrict__ a0, const float* __restrict__ b0,
           const float* __restrict__ a1, const float* __restrict__ b1,
           const float* __restrict__ a2, const float* __restrict__ b2,
           const float* __restrict__ a3, const float* __restrict__ b3,
           float* __restrict__ out, float* __restrict__ ws)
{
    __shared__ float smem[SMEM_FLOATS];
    const int blk = blockIdx.x;
    if (blk < GB_L0) {
        corr_level<64, 112, 112, 2, 56, 4, 14, 1, 8, 0>(
            a0, b0, out + OFF0, blk, smem);
    } else if (blk < GB_L0 + GB_L1) {
        corr_level<128, 56, 56, 4, 28, 4, 7, 2, 8, PMODE>(
            a1, b1, PMODE == 1 ? ws + WS_L1 : out + OFF1, blk - GB_L0, smem);
    } else if (blk < GB_L0 + GB_L1 + GB_L2) {
        corr_level<256, 28, 28, 4, 28, 4, 7, 4, 8, PMODE>(
            a2, b2, PMODE == 1 ? ws + WS_L2 : out + OFF2, blk - (GB_L0 + GB_L1), smem);
    } else {
        corr_level<512, 14, 14, 14, 14, 7, 2, 16, 8, PMODE>(
            a3, b3, PMODE == 1 ? ws + WS_L3 : out + OFF3,
            blk - (GB_L0 + GB_L1 + GB_L2), smem);
    }
}

// One dispatch reducing all three partial regions into d_out.
__global__ void __launch_bounds__(THREADS)
reduce_all_kernel(const float* __restrict__ ws, float* __restrict__ out)
{
    const int blk = blockIdx.x;
    const float4* src; float4* dst; int n4, chunks, nb, base;
    if (blk < 96)       { src = (const float4*)(ws + WS_L3); dst = (float4*)(out + OFF3);
                          n4 = N3 / 4; chunks = 16; nb = 96;  base = 0; }
    else if (blk < 224) { src = (const float4*)(ws + WS_L2); dst = (float4*)(out + OFF2);
                          n4 = N2 / 4; chunks = 4;  nb = 128; base = 96; }
    else                { src = (const float4*)(ws + WS_L1); dst = (float4*)(out + OFF1);
                          n4 = N1 / 4; chunks = 2;  nb = 288; base = 224; }
    for (int i = (blk - base) * THREADS + threadIdx.x; i < n4; i += nb * THREADS) {
        float4 sv = src[i];
        for (int k = 1; k < chunks; ++k) {
            float4 tv = src[(size_t)k * n4 + i];
            sv.x += tv.x; sv.y += tv.y; sv.z += tv.z; sv.w += tv.w;
        }
        dst[i] = sv;
    }
}

extern "C" void kernel_launch(void* const* d_in, const int* in_sizes, int n_in,
                              void* d_out, int out_size, void* d_ws, size_t ws_size,
                              hipStream_t stream) {
    // setup_inputs() dict order: rgb0, depth0, rgb1, depth1, rgb2, depth2, rgb3, depth3
    const float* a0 = (const float*)d_in[0];
    const float* b0 = (const float*)d_in[1];
    const float* a1 = (const float*)d_in[2];
    const float* b1 = (const float*)d_in[3];
    const float* a2 = (const float*)d_in[4];
    const float* b2 = (const float*)d_in[5];
    const float* a3 = (const float*)d_in[6];
    const float* b3 = (const float*)d_in[7];
    float* out = (float*)d_out;
    float* ws  = (float*)d_ws;

    if (ws_size >= WS_BYTES) {
        hipLaunchKernelGGL((corr_fused<1>), dim3(GB_TOT), dim3(THREADS), 0, stream,
                           a0, b0, a1, b1, a2, b2, a3, b3, out, ws);
        hipLaunchKernelGGL(reduce_all_kernel, dim3(512), dim3(THREADS), 0, stream,
                           ws, out);
    } else {
        hipLaunchKernelGGL(zero_region_kernel, dim3(512), dim3(THREADS), 0, stream,
                           out, OFF0);
        hipLaunchKernelGGL((corr_fused<2>), dim3(GB_TOT), dim3(THREADS), 0, stream,
                           a0, b0, a1, b1, a2, b2, a3, b3, out, ws);
    }
}

// Round 11
// 107.129 us; speedup vs baseline: 4.8107x; 1.0898x over previous
//
#include <hip/hip_runtime.h>

#define THREADS 256

// d_out = concat(corr3, corr2, corr1, corr0), fp32.
// corr[bb, pi, pj, i, j] = sum_c a[bb,c,i,j] * bpad[bb,c, i+pi-4, j+pj-4]
// Input mapping: d_in = rgb0, depth0, rgb1, depth1, ... (interleaved).
#define OFF3 0
#define OFF2 127008        // 8*81*14*14
#define OFF1 635040        // OFF2 + 8*81*28*28
#define OFF0 2667168       // OFF1 + 8*81*56*56

// Workspace layout (floats): L1 partials | L2 partials | L3 partials
#define N1 2032128
#define N2 508032
#define N3 127008
#define WS_L1 0
#define WS_L2 (2 * N1)
#define WS_L3 (WS_L2 + 4 * N2)
#define WS_FLOATS (WS_L3 + 16 * N3)
#define WS_BYTES ((size_t)WS_FLOATS * 4)

// fused-grid segmentation
#define GB_L0 896          // 8 bb * 56 i-tiles * 2 j-tiles
#define GB_L1 448          // 8 * 14 * 2 * 2 chunks
#define GB_L2 224          // 8 * 7 * 4 chunks
#define GB_L3 128          // 8 * 16 chunks
#define GB_TOT (GB_L0 + GB_L1 + GB_L2 + GB_L3)   // 1696

#define SMEM_FLOATS 10880  // 2 buffers * max(CB*BPC) = 2*8*(10*68) (L0)

__global__ void __launch_bounds__(THREADS)
zero_region_kernel(float* __restrict__ p, int n) {
    int i = blockIdx.x * blockDim.x + threadIdx.x;
    int stride = gridDim.x * blockDim.x;
    for (; i < n; i += stride) p[i] = 0.f;
}

// Block = (bb, i-tile, j-tile, channel-chunk). Thread tid -> (ii, pi, strip s).
// LDS double-buffered: issue loads(cg+1) -> compute(cg, bufA) -> ds_write(cg+1, bufB)
// -> barrier.  a is read directly from global during compute.
// MODE 0: direct store; MODE 1: per-chunk partial region; MODE 2: atomicAdd.
template<int C, int H, int W, int TI, int TW, int SJ, int STRIPS, int CHUNKS,
         int CB, int MODE>
__device__ __forceinline__ void corr_level(const float* __restrict__ a,
                                           const float* __restrict__ b,
                                           float* __restrict__ out,
                                           int blk, float* __restrict__ smem)
{
    constexpr int PER_I = 9 * STRIPS;
    constexpr int USED  = TI * PER_I;                   // 252 at every level
    constexpr int BW_   = ((TW + 8 + 3) / 4) * 4 + 4;   // row stride, != 0 mod 32
    constexpr int BROWS = TI + 8;
    constexpr int CCH   = C / CHUNKS;
    constexpr int HT    = H / TI;
    constexpr int WT    = W / TW;
    constexpr int NOUT  = 8 * 81 * H * W;
    constexpr int HW    = H * W;
    constexpr int BPC   = BROWS * BW_;                  // staged floats per channel
    constexpr bool F4   = (W % 4 == 0) && (TW % 4 == 0) && (SJ % 4 == 0);
    constexpr int NG    = CCH / CB;
    static_assert(USED <= THREADS, "thread mapping overflow");
    static_assert(SJ * STRIPS == TW, "strips must cover TW");
    static_assert(CCH % CB == 0, "CB must divide channels per chunk");
    static_assert(NG % 2 == 0, "double-buffer loop assumes even group count");
    static_assert(2 * CB * BPC <= SMEM_FLOATS, "smem overflow");

    const int ch = blk % CHUNKS;
    int t = blk / CHUNKS;
    const int jt = t % WT; t /= WT;
    const int it = t % HT;
    const int bb = t / HT;
    const int i0 = it * TI;
    const int jb = jt * TW;

    const int tid = threadIdx.x;
    const int ii  = tid / PER_I;
    const int rem = tid - ii * PER_I;
    const int pi  = rem / STRIPS;
    const int s   = rem - pi * STRIPS;
    const int j0  = s * SJ;
    const bool active = (tid < USED);

    const int c0 = ch * CCH;
    const float* __restrict__ bp = b + (size_t)(bb * C + c0) * HW;
    const float* __restrict__ ap = a + (size_t)(bb * C + c0) * HW;

    float* buf0 = smem;
    float* buf1 = smem + CB * BPC;

    float acc[9][SJ];
    #pragma unroll
    for (int p = 0; p < 9; ++p)
        #pragma unroll
        for (int u = 0; u < SJ; ++u) acc[p][u] = 0.f;

    // ---------- staging machinery (b only) ----------
    constexpr int F4PR = BW_ / 4;                  // float4 slots per row
    constexpr int NBF4 = BROWS * F4PR;
    constexpr int TOT4 = CB * NBF4;
    constexpr int K4   = (TOT4 + THREADS - 1) / THREADS;
    constexpr int TOTS = CB * BPC;
    constexpr int KS   = (TOTS + THREADS - 1) / THREADS;

    float4 pre4[F4 ? K4 : 1];
    float  pres[F4 ? 1 : KS];

    auto load_group = [&](int cg) {
        const float* bg = bp + (size_t)(cg * CB) * HW;
        if constexpr (F4) {
            #pragma unroll
            for (int k = 0; k < K4; ++k) {
                const int f = tid + k * THREADS;
                float4 v = {0.f, 0.f, 0.f, 0.f};
                if (f < TOT4) {
                    const int cb  = f / NBF4;
                    const int f2  = f - cb * NBF4;
                    const int row = f2 / F4PR;
                    const int c4  = f2 - row * F4PR;
                    const int r   = i0 + row - 4;
                    const int jj  = jb + (c4 - 1) * 4;
                    if ((unsigned)r < (unsigned)H && jj >= 0 && jj <= W - 4)
                        v = *reinterpret_cast<const float4*>(&bg[(size_t)cb * HW + r * W + jj]);
                }
                pre4[k] = v;
            }
        } else {
            #pragma unroll
            for (int k = 0; k < KS; ++k) {
                const int f = tid + k * THREADS;
                float v = 0.f;
                if (f < TOTS) {
                    const int cb  = f / BPC;
                    const int f2  = f - cb * BPC;
                    const int row = f2 / BW_;
                    const int col = f2 - row * BW_;
                    const int r   = i0 + row - 4;
                    const int jj  = jb + col - 4;
                    if ((unsigned)r < (unsigned)H && (unsigned)jj < (unsigned)W)
                        v = bg[(size_t)cb * HW + r * W + jj];
                }
                pres[k] = v;
            }
        }
    };
    auto store_group = [&](float* dst) {
        if constexpr (F4) {
            #pragma unroll
            for (int k = 0; k < K4; ++k) {
                const int f = tid + k * THREADS;
                if (f < TOT4) {
                    const int cb  = f / NBF4;
                    const int f2  = f - cb * NBF4;
                    const int row = f2 / F4PR;
                    const int c4  = f2 - row * F4PR;
                    *reinterpret_cast<float4*>(&dst[cb * BPC + row * BW_ + c4 * 4]) = pre4[k];
                }
            }
        } else {
            #pragma unroll
            for (int k = 0; k < KS; ++k) {
                const int f = tid + k * THREADS;
                if (f < TOTS) dst[f] = pres[k];
            }
        }
    };
    auto compute = [&](int cg, const float* buf) {
        if (!active) return;
        const float* agbase = ap + (size_t)(cg * CB) * HW
                            + (size_t)(i0 + ii) * W + jb + j0;
        #pragma unroll
        for (int cb = 0; cb < CB; ++cb) {
            float breg[SJ + 8];
            float areg[SJ];
            const float* bbase = &buf[cb * BPC + (ii + pi) * BW_ + j0];
            const float* ac    = agbase + (size_t)cb * HW;
            if constexpr (F4) {
                #pragma unroll
                for (int k = 0; k < (SJ + 8) / 4; ++k) {
                    float4 v = *reinterpret_cast<const float4*>(&bbase[4 * k]);
                    breg[4*k+0] = v.x; breg[4*k+1] = v.y;
                    breg[4*k+2] = v.z; breg[4*k+3] = v.w;
                }
                #pragma unroll
                for (int u = 0; u < SJ / 4; ++u) {
                    float4 v = *reinterpret_cast<const float4*>(&ac[4 * u]);
                    areg[4*u+0] = v.x; areg[4*u+1] = v.y;
                    areg[4*u+2] = v.z; areg[4*u+3] = v.w;
                }
            } else {
                #pragma unroll
                for (int k = 0; k < SJ + 8; ++k) breg[k] = bbase[k];
                #pragma unroll
                for (int u = 0; u < SJ; ++u) areg[u] = ac[u];
            }
            #pragma unroll
            for (int pj = 0; pj < 9; ++pj)
                #pragma unroll
                for (int u = 0; u < SJ; ++u)
                    acc[pj][u] = fmaf(areg[u], breg[u + pj], acc[pj][u]);
        }
    };

    // ---------- double-buffered main loop (1 barrier per group) ----------
    load_group(0);
    store_group(buf0);
    __syncthreads();
    for (int cg = 0; cg < NG; cg += 2) {
        // even group: compute buf0, stage cg+1 into buf1
        if (cg + 1 < NG) load_group(cg + 1);
        compute(cg, buf0);
        if (cg + 1 < NG) store_group(buf1);
        __syncthreads();
        if (cg + 1 < NG) {
            // odd group: compute buf1, stage cg+2 into buf0
            if (cg + 2 < NG) load_group(cg + 2);
            compute(cg + 1, buf1);
            if (cg + 2 < NG) store_group(buf0);
            __syncthreads();
        }
    }

    if (active) {
        const int i = i0 + ii;
        float* obase = out;
        if constexpr (MODE == 1) obase = out + (size_t)ch * NOUT;
        #pragma unroll
        for (int pj = 0; pj < 9; ++pj) {
            float* o = obase + ((size_t)((bb * 9 + pi) * 9 + pj) * H + i) * W + jb + j0;
            if constexpr (MODE == 2) {
                #pragma unroll
                for (int u = 0; u < SJ; ++u) atomicAdd(&o[u], acc[pj][u]);
            } else if constexpr (F4) {
                #pragma unroll
                for (int u = 0; u < SJ / 4; ++u) {
                    float4 v;
                    v.x = acc[pj][4*u+0]; v.y = acc[pj][4*u+1];
                    v.z = acc[pj][4*u+2]; v.w = acc[pj][4*u+3];
                    *reinterpret_cast<float4*>(&o[4 * u]) = v;
                }
            } else {
                #pragma unroll
                for (int u = 0; u < SJ; ++u) o[u] = acc[pj][u];
            }
        }
    }
}

// All four levels in ONE dispatch so the small grids overlap with L0.
// PMODE: 1 = ws partial-sum path, 2 = atomic fallback (L0 is MODE 0 in both).
template<int PMODE>
__global__ void __launch_bounds__(THREADS)
corr_fused(const float* __restrict__ a0, const float* __restrict__ b0,
           const float* __restrict__ a1, const float* __restrict__ b1,
           const float* __restrict__ a2, const float* __restrict__ b2,
           const float* __restrict__ a3, const float* __restrict__ b3,
           float* __restrict__ out, float* __restrict__ ws)
{
    __shared__ float smem[SMEM_FLOATS];
    const int blk = blockIdx.x;
    if (blk < GB_L0) {
        corr_level<64, 112, 112, 2, 56, 4, 14, 1, 8, 0>(
            a0, b0, out + OFF0, blk, smem);
    } else if (blk < GB_L0 + GB_L1) {
        corr_level<128, 56, 56, 4, 28, 4, 7, 2, 8, PMODE>(
            a1, b1, PMODE == 1 ? ws + WS_L1 : out + OFF1, blk - GB_L0, smem);
    } else if (blk < GB_L0 + GB_L1 + GB_L2) {
        corr_level<256, 28, 28, 4, 28, 4, 7, 4, 8, PMODE>(
            a2, b2, PMODE == 1 ? ws + WS_L2 : out + OFF2, blk - (GB_L0 + GB_L1), smem);
    } else {
        corr_level<512, 14, 14, 14, 14, 7, 2, 16, 8, PMODE>(
            a3, b3, PMODE == 1 ? ws + WS_L3 : out + OFF3,
            blk - (GB_L0 + GB_L1 + GB_L2), smem);
    }
}

// One dispatch reducing all three partial regions into d_out.
__global__ void __launch_bounds__(THREADS)
reduce_all_kernel(const float* __restrict__ ws, float* __restrict__ out)
{
    const int blk = blockIdx.x;
    const float4* src; float4* dst; int n4, chunks, nb, base;
    if (blk < 96)       { src = (const float4*)(ws + WS_L3); dst = (float4*)(out + OFF3);
                          n4 = N3 / 4; chunks = 16; nb = 96;  base = 0; }
    else if (blk < 224) { src = (const float4*)(ws + WS_L2); dst = (float4*)(out + OFF2);
                          n4 = N2 / 4; chunks = 4;  nb = 128; base = 96; }
    else                { src = (const float4*)(ws + WS_L1); dst = (float4*)(out + OFF1);
                          n4 = N1 / 4; chunks = 2;  nb = 288; base = 224; }
    for (int i = (blk - base) * THREADS + threadIdx.x; i < n4; i += nb * THREADS) {
        float4 sv = src[i];
        for (int k = 1; k < chunks; ++k) {
            float4 tv = src[(size_t)k * n4 + i];
            sv.x += tv.x; sv.y += tv.y; sv.z += tv.z; sv.w += tv.w;
        }
        dst[i] = sv;
    }
}

extern "C" void kernel_launch(void* const* d_in, const int* in_sizes, int n_in,
                              void* d_out, int out_size, void* d_ws, size_t ws_size,
                              hipStream_t stream) {
    // setup_inputs() dict order: rgb0, depth0, rgb1, depth1, rgb2, depth2, rgb3, depth3
    const float* a0 = (const float*)d_in[0];
    const float* b0 = (const float*)d_in[1];
    const float* a1 = (const float*)d_in[2];
    const float* b1 = (const float*)d_in[3];
    const float* a2 = (const float*)d_in[4];
    const float* b2 = (const float*)d_in[5];
    const float* a3 = (const float*)d_in[6];
    const float* b3 = (const float*)d_in[7];
    float* out = (float*)d_out;
    float* ws  = (float*)d_ws;

    if (ws_size >= WS_BYTES) {
        hipLaunchKernelGGL((corr_fused<1>), dim3(GB_TOT), dim3(THREADS), 0, stream,
                           a0, b0, a1, b1, a2, b2, a3, b3, out, ws);
        hipLaunchKernelGGL(reduce_all_kernel, dim3(512), dim3(THREADS), 0, stream,
                           ws, out);
    } else {
        hipLaunchKernelGGL(zero_region_kernel, dim3(512), dim3(THREADS), 0, stream,
                           out, OFF0);
        hipLaunchKernelGGL((corr_fused<2>), dim3(GB_TOT), dim3(THREADS), 0, stream,
                           a0, b0, a1, b1, a2, b2, a3, b3, out, ws);
    }
}